// Round 4
// baseline (407.767 us; speedup 1.0000x reference)
//
#include <hip/hip_runtime.h>

#define NN 100000
#define NE 1600000
#define ALPHA 0.2f

#define SCAN_CHUNK 1024
#define NBLK ((NN + SCAN_CHUNK - 1) / SCAN_CHUNK)   // 98

// ---------------- bf16 helpers (RNE pack, cheap unpack) ---------------------
__device__ __forceinline__ unsigned short f2bf(float f) {
    unsigned int u = __builtin_bit_cast(unsigned int, f);
    u += 0x7FFFu + ((u >> 16) & 1u);
    return (unsigned short)(u >> 16);
}
__device__ __forceinline__ float bf2f(unsigned short u) {
    return __builtin_bit_cast(float, (unsigned int)u << 16);
}

// ---------------- DPP 16-lane sum (all VALU, no DS pipe) --------------------
template<int CTRL>
__device__ __forceinline__ float dpp_add(float x) {
    int y = __builtin_amdgcn_update_dpp(0, __builtin_bit_cast(int, x),
                                        CTRL, 0xF, 0xF, true);
    return x + __builtin_bit_cast(float, y);
}
__device__ __forceinline__ float red16(float x) {
    x = dpp_add<0xB1>(x);    // quad_perm(1,0,3,2)  : xor 1
    x = dpp_add<0x4E>(x);    // quad_perm(2,3,0,1)  : xor 2
    x = dpp_add<0x141>(x);   // row_half_mirror     : combine quads in 8
    x = dpp_add<0x140>(x);   // row_mirror          : combine 8s in 16
    return x;
}

// ---------------------------------------------------------------------------
// Kernel 1: node transform  Q = nf@Wq + bq (fp32), Vb = bf16(nf@Wv + bv)
// ---------------------------------------------------------------------------
__global__ __launch_bounds__(256) void transform_kernel(
    const float* __restrict__ nf, const float* __restrict__ Wq, const float* __restrict__ bq,
    const float* __restrict__ Wv, const float* __restrict__ bv,
    float* __restrict__ q, unsigned short* __restrict__ vbf)
{
    __shared__ float sWq[64][64];
    __shared__ float sWv[64][64];
    __shared__ float sX[16][64];
    for (int i = threadIdx.x; i < 4096; i += 256) {
        sWq[i >> 6][i & 63] = Wq[i];
        sWv[i >> 6][i & 63] = Wv[i];
    }
    const int j  = threadIdx.x & 63;
    const int r0 = threadIdx.x >> 6;
    const float bqj = bq[j], bvj = bv[j];
    __syncthreads();

    const int ngroups = (NN + 15) >> 4;
    for (int g = blockIdx.x; g < ngroups; g += gridDim.x) {
        const int base = g << 4;
        #pragma unroll
        for (int i = 0; i < 4; i++) {
            int idx = threadIdx.x + i * 256;
            int row = base + (idx >> 6);
            sX[idx >> 6][idx & 63] = (row < NN) ? nf[(size_t)row * 64 + (idx & 63)] : 0.0f;
        }
        __syncthreads();

        float aq0 = bqj, aq1 = bqj, aq2 = bqj, aq3 = bqj;
        float av0 = bvj, av1 = bvj, av2 = bvj, av3 = bvj;
        #pragma unroll 8
        for (int k = 0; k < 64; k++) {
            float wq = sWq[k][j], wv = sWv[k][j];
            float x0 = sX[r0 * 4 + 0][k];
            float x1 = sX[r0 * 4 + 1][k];
            float x2 = sX[r0 * 4 + 2][k];
            float x3 = sX[r0 * 4 + 3][k];
            aq0 += x0 * wq; av0 += x0 * wv;
            aq1 += x1 * wq; av1 += x1 * wv;
            aq2 += x2 * wq; av2 += x2 * wv;
            aq3 += x3 * wq; av3 += x3 * wv;
        }
        const int row = base + r0 * 4;
        float aqs[4] = {aq0, aq1, aq2, aq3};
        float avs[4] = {av0, av1, av2, av3};
        #pragma unroll
        for (int i = 0; i < 4; i++)
            if (row + i < NN) {
                q[(size_t)(row + i) * 64 + j]   = aqs[i];
                vbf[(size_t)(row + i) * 64 + j] = f2bf(avs[i]);
            }
        __syncthreads();
    }
}

// ---------------------------------------------------------------------------
// CSR build: histogram -> 3-kernel two-level scan -> scatter
// ---------------------------------------------------------------------------
__global__ __launch_bounds__(256) void hist_kernel(
    const int* __restrict__ etgt, int* __restrict__ cnt)
{
    int e = blockIdx.x * 256 + threadIdx.x;
    if (e < NE) atomicAdd(&cnt[etgt[e]], 1);
}

__global__ __launch_bounds__(256) void scan_partial_kernel(
    const int* __restrict__ cnt, int* __restrict__ bsum)
{
    const int b = blockIdx.x;
    const int base = b * SCAN_CHUNK + threadIdx.x * 4;
    int s = 0;
    #pragma unroll
    for (int i = 0; i < 4; i++) {
        int idx = base + i;
        if (idx < NN) s += cnt[idx];
    }
    #pragma unroll
    for (int off = 1; off < 64; off <<= 1) s += __shfl_xor(s, off);
    __shared__ int ws[4];
    if ((threadIdx.x & 63) == 0) ws[threadIdx.x >> 6] = s;
    __syncthreads();
    if (threadIdx.x == 0) bsum[b] = ws[0] + ws[1] + ws[2] + ws[3];
}

__global__ __launch_bounds__(128) void scan_bsums_kernel(
    int* __restrict__ bsum, int* __restrict__ offs)
{
    __shared__ int s[128];
    const int t = threadIdx.x;
    int val = (t < NBLK) ? bsum[t] : 0;
    s[t] = val;
    __syncthreads();
    for (int off = 1; off < 128; off <<= 1) {
        int tv = (t >= off) ? s[t - off] : 0;
        __syncthreads();
        s[t] += tv;
        __syncthreads();
    }
    if (t < NBLK) bsum[t] = s[t] - val;   // exclusive prefix
    if (t == 0)   offs[NN] = NE;
}

__global__ __launch_bounds__(256) void scan_final_kernel(
    const int* __restrict__ cnt, const int* __restrict__ bsum,
    int* __restrict__ offs, int* __restrict__ cursor)
{
    const int b = blockIdx.x;
    const int base = b * SCAN_CHUNK + threadIdx.x * 4;
    int c0 = 0, c1 = 0, c2 = 0, c3 = 0;
    if (base + 0 < NN) c0 = cnt[base + 0];
    if (base + 1 < NN) c1 = cnt[base + 1];
    if (base + 2 < NN) c2 = cnt[base + 2];
    if (base + 3 < NN) c3 = cnt[base + 3];
    int tsum = c0 + c1 + c2 + c3;

    const int lanex = threadIdx.x & 63;
    int incl = tsum;
    #pragma unroll
    for (int off = 1; off < 64; off <<= 1) {
        int t = __shfl_up(incl, off);
        if (lanex >= off) incl += t;
    }
    __shared__ int wsum[4];
    if (lanex == 63) wsum[threadIdx.x >> 6] = incl;
    __syncthreads();
    int wbase = 0;
    const int wid = threadIdx.x >> 6;
    for (int w = 0; w < 4; w++) if (w < wid) wbase += wsum[w];
    int run = bsum[b] + wbase + (incl - tsum);

    if (base + 0 < NN) { offs[base + 0] = run; cursor[base + 0] = run; run += c0; }
    if (base + 1 < NN) { offs[base + 1] = run; cursor[base + 1] = run; run += c1; }
    if (base + 2 < NN) { offs[base + 2] = run; cursor[base + 2] = run; run += c2; }
    if (base + 3 < NN) { offs[base + 3] = run; cursor[base + 3] = run; }
}

__global__ __launch_bounds__(256) void scatter_kernel(
    const int* __restrict__ esrc, const int* __restrict__ etgt,
    int* __restrict__ cursor, int* __restrict__ ssrc)
{
    int e = blockIdx.x * 256 + threadIdx.x;
    if (e < NE) {
        int t = etgt[e];
        int p = atomicAdd(&cursor[t], 1);
        ssrc[p] = esrc[e];
    }
}

// ---------------------------------------------------------------------------
// Gather kernel: one 64-lane wave per node, lane = h*16+c.
// bf16 V rows (128B/row gather), DPP 16-lane logit reduce, 2-edge unroll
// with 4-deep value prefetch. No atomics, output written once.
// ---------------------------------------------------------------------------
__device__ __forceinline__ float ldv(const unsigned short* __restrict__ vb,
                                     int src, int lane) {
    return bf2f(vb[(size_t)src * 64 + lane]);
}

__global__ __launch_bounds__(256) void gather_kernel(
    const float* __restrict__ q, const unsigned short* __restrict__ vb,
    const float* __restrict__ ak,   // [16][4] row-major: ak[c*4+h]
    const int* __restrict__ offs, const int* __restrict__ ssrc,
    float* __restrict__ out)
{
    const int node = (blockIdx.x * 256 + threadIdx.x) >> 6;
    const int lane = threadIdx.x & 63;
    if (node >= NN) return;
    const int h = lane >> 4;
    const int c = lane & 15;
    const float akl = ak[c * 4 + h];
    const float qv  = q[(size_t)node * 64 + lane];
    const int start = offs[node];
    const int end   = offs[node + 1];

    float acc = 0.0f, wsum = 0.0f;

    float v0 = 0.f, v1 = 0.f, v2 = 0.f, v3 = 0.f;
    if (start + 0 < end) v0 = ldv(vb, ssrc[start + 0], lane);
    if (start + 1 < end) v1 = ldv(vb, ssrc[start + 1], lane);
    if (start + 2 < end) v2 = ldv(vb, ssrc[start + 2], lane);
    if (start + 3 < end) v3 = ldv(vb, ssrc[start + 3], lane);

    int p = start;
    for (; p + 1 < end; p += 2) {
        float a = v0, b = v1;
        v0 = v2; v1 = v3;
        if (p + 4 < end) v2 = ldv(vb, ssrc[p + 4], lane);
        if (p + 5 < end) v3 = ldv(vb, ssrc[p + 5], lane);
        float fa = qv + a; fa = fa > 0.f ? fa : ALPHA * fa;
        float fb = qv + b; fb = fb > 0.f ? fb : ALPHA * fb;
        float xa = red16(fa * akl);
        float xb = red16(fb * akl);
        float wa = __expf(xa);
        float wb = __expf(xb);
        wsum += wa + wb;
        acc  += wa * a;
        acc  += wb * b;
    }
    if (p < end) {
        float a = v0;
        float fa = qv + a; fa = fa > 0.f ? fa : ALPHA * fa;
        float xa = red16(fa * akl);
        float wa = __expf(xa);
        wsum += wa;
        acc  += wa * a;
    }

    if (wsum <= 0.0f) wsum = 1.0f;
    float r = acc / wsum;
    out[(size_t)node * 64 + lane] = r > 0.0f ? r : ALPHA * r;
}

extern "C" void kernel_launch(void* const* d_in, const int* in_sizes, int n_in,
                              void* d_out, int out_size, void* d_ws, size_t ws_size,
                              hipStream_t stream) {
    const float* nf   = (const float*)d_in[0];
    const float* Wq   = (const float*)d_in[1];
    const float* bq   = (const float*)d_in[2];
    const float* Wv   = (const float*)d_in[3];
    const float* bv   = (const float*)d_in[4];
    const float* ak   = (const float*)d_in[5];
    const int*   esrc = (const int*)d_in[6];
    const int*   etgt = (const int*)d_in[7];
    float* out = (float*)d_out;

    // workspace layout:
    //   q:      NN*64 f32   (25.6 MB)
    //   vbf:    NN*64 u16   (12.8 MB)
    //   cnt:    NN    i32
    //   offs:   NN+1  i32
    //   cursor: NN    i32
    //   ssrc:   NE    i32
    //   bsum:   NBLK  i32
    float*          q      = (float*)d_ws;
    unsigned short* vbf    = (unsigned short*)(q + (size_t)NN * 64);
    int*            cnt    = (int*)(vbf + (size_t)NN * 64);
    int*            offs   = cnt + NN;
    int*            cursor = offs + (NN + 1);
    int*            ssrc   = cursor + NN;
    int*            bsum   = ssrc + NE;

    hipMemsetAsync(cnt, 0, (size_t)NN * sizeof(int), stream);

    transform_kernel<<<1024, 256, 0, stream>>>(nf, Wq, bq, Wv, bv, q, vbf);
    hist_kernel<<<(NE + 255) / 256, 256, 0, stream>>>(etgt, cnt);
    scan_partial_kernel<<<NBLK, 256, 0, stream>>>(cnt, bsum);
    scan_bsums_kernel<<<1, 128, 0, stream>>>(bsum, offs);
    scan_final_kernel<<<NBLK, 256, 0, stream>>>(cnt, bsum, offs, cursor);
    scatter_kernel<<<(NE + 255) / 256, 256, 0, stream>>>(esrc, etgt, cursor, ssrc);
    gather_kernel<<<(NN * 64 + 255) / 256, 256, 0, stream>>>(q, vbf, ak, offs, ssrc, out);
}

// Round 5
// 346.289 us; speedup vs baseline: 1.1775x; 1.1775x over previous
//
#include <hip/hip_runtime.h>

#define NN 100000
#define NE 1600000
#define ALPHA 0.2f

#define SCAN_CHUNK 1024
#define NBLK ((NN + SCAN_CHUNK - 1) / SCAN_CHUNK)   // 98

// ---------------- bf16 helpers (RNE pack, cheap unpack) ---------------------
__device__ __forceinline__ unsigned short f2bf(float f) {
    unsigned int u = __builtin_bit_cast(unsigned int, f);
    u += 0x7FFFu + ((u >> 16) & 1u);
    return (unsigned short)(u >> 16);
}
__device__ __forceinline__ float bf2f(unsigned short u) {
    return __builtin_bit_cast(float, (unsigned int)u << 16);
}

// ---------------- DPP 16-lane sum (all VALU, no DS pipe) --------------------
template<int CTRL>
__device__ __forceinline__ float dpp_add(float x) {
    int y = __builtin_amdgcn_update_dpp(0, __builtin_bit_cast(int, x),
                                        CTRL, 0xF, 0xF, true);
    return x + __builtin_bit_cast(float, y);
}
__device__ __forceinline__ float red16(float x) {
    x = dpp_add<0xB1>(x);    // quad_perm(1,0,3,2)  : xor 1
    x = dpp_add<0x4E>(x);    // quad_perm(2,3,0,1)  : xor 2
    x = dpp_add<0x141>(x);   // row_half_mirror     : combine quads in 8
    x = dpp_add<0x140>(x);   // row_mirror          : combine 8s in 16
    return x;
}

// ---------------------------------------------------------------------------
// Kernel 1: node transform  Qb = bf16(nf@Wq + bq), Vb = bf16(nf@Wv + bv)
// ---------------------------------------------------------------------------
__global__ __launch_bounds__(256) void transform_kernel(
    const float* __restrict__ nf, const float* __restrict__ Wq, const float* __restrict__ bq,
    const float* __restrict__ Wv, const float* __restrict__ bv,
    unsigned short* __restrict__ qbf, unsigned short* __restrict__ vbf)
{
    __shared__ float sWq[64][64];
    __shared__ float sWv[64][64];
    __shared__ float sX[16][64];
    for (int i = threadIdx.x; i < 4096; i += 256) {
        sWq[i >> 6][i & 63] = Wq[i];
        sWv[i >> 6][i & 63] = Wv[i];
    }
    const int j  = threadIdx.x & 63;
    const int r0 = threadIdx.x >> 6;
    const float bqj = bq[j], bvj = bv[j];
    __syncthreads();

    const int ngroups = (NN + 15) >> 4;
    for (int g = blockIdx.x; g < ngroups; g += gridDim.x) {
        const int base = g << 4;
        #pragma unroll
        for (int i = 0; i < 4; i++) {
            int idx = threadIdx.x + i * 256;
            int row = base + (idx >> 6);
            sX[idx >> 6][idx & 63] = (row < NN) ? nf[(size_t)row * 64 + (idx & 63)] : 0.0f;
        }
        __syncthreads();

        float aq0 = bqj, aq1 = bqj, aq2 = bqj, aq3 = bqj;
        float av0 = bvj, av1 = bvj, av2 = bvj, av3 = bvj;
        #pragma unroll 8
        for (int k = 0; k < 64; k++) {
            float wq = sWq[k][j], wv = sWv[k][j];
            float x0 = sX[r0 * 4 + 0][k];
            float x1 = sX[r0 * 4 + 1][k];
            float x2 = sX[r0 * 4 + 2][k];
            float x3 = sX[r0 * 4 + 3][k];
            aq0 += x0 * wq; av0 += x0 * wv;
            aq1 += x1 * wq; av1 += x1 * wv;
            aq2 += x2 * wq; av2 += x2 * wv;
            aq3 += x3 * wq; av3 += x3 * wv;
        }
        const int row = base + r0 * 4;
        float aqs[4] = {aq0, aq1, aq2, aq3};
        float avs[4] = {av0, av1, av2, av3};
        #pragma unroll
        for (int i = 0; i < 4; i++)
            if (row + i < NN) {
                qbf[(size_t)(row + i) * 64 + j] = f2bf(aqs[i]);
                vbf[(size_t)(row + i) * 64 + j] = f2bf(avs[i]);
            }
        __syncthreads();
    }
}

// ---------------------------------------------------------------------------
// CSR build: histogram -> 3-kernel two-level scan -> scatter
// ---------------------------------------------------------------------------
__global__ __launch_bounds__(256) void hist_kernel(
    const int* __restrict__ etgt, int* __restrict__ cnt)
{
    int e = blockIdx.x * 256 + threadIdx.x;
    if (e < NE) atomicAdd(&cnt[etgt[e]], 1);
}

__global__ __launch_bounds__(256) void scan_partial_kernel(
    const int* __restrict__ cnt, int* __restrict__ bsum)
{
    const int b = blockIdx.x;
    const int base = b * SCAN_CHUNK + threadIdx.x * 4;
    int s = 0;
    #pragma unroll
    for (int i = 0; i < 4; i++) {
        int idx = base + i;
        if (idx < NN) s += cnt[idx];
    }
    #pragma unroll
    for (int off = 1; off < 64; off <<= 1) s += __shfl_xor(s, off);
    __shared__ int ws[4];
    if ((threadIdx.x & 63) == 0) ws[threadIdx.x >> 6] = s;
    __syncthreads();
    if (threadIdx.x == 0) bsum[b] = ws[0] + ws[1] + ws[2] + ws[3];
}

__global__ __launch_bounds__(128) void scan_bsums_kernel(
    int* __restrict__ bsum, int* __restrict__ offs)
{
    __shared__ int s[128];
    const int t = threadIdx.x;
    int val = (t < NBLK) ? bsum[t] : 0;
    s[t] = val;
    __syncthreads();
    for (int off = 1; off < 128; off <<= 1) {
        int tv = (t >= off) ? s[t - off] : 0;
        __syncthreads();
        s[t] += tv;
        __syncthreads();
    }
    if (t < NBLK) bsum[t] = s[t] - val;   // exclusive prefix
    if (t == 0)   offs[NN] = NE;
}

__global__ __launch_bounds__(256) void scan_final_kernel(
    const int* __restrict__ cnt, const int* __restrict__ bsum,
    int* __restrict__ offs, int* __restrict__ cursor)
{
    const int b = blockIdx.x;
    const int base = b * SCAN_CHUNK + threadIdx.x * 4;
    int c0 = 0, c1 = 0, c2 = 0, c3 = 0;
    if (base + 0 < NN) c0 = cnt[base + 0];
    if (base + 1 < NN) c1 = cnt[base + 1];
    if (base + 2 < NN) c2 = cnt[base + 2];
    if (base + 3 < NN) c3 = cnt[base + 3];
    int tsum = c0 + c1 + c2 + c3;

    const int lanex = threadIdx.x & 63;
    int incl = tsum;
    #pragma unroll
    for (int off = 1; off < 64; off <<= 1) {
        int t = __shfl_up(incl, off);
        if (lanex >= off) incl += t;
    }
    __shared__ int wsum[4];
    if (lanex == 63) wsum[threadIdx.x >> 6] = incl;
    __syncthreads();
    int wbase = 0;
    const int wid = threadIdx.x >> 6;
    for (int w = 0; w < 4; w++) if (w < wid) wbase += wsum[w];
    int run = bsum[b] + wbase + (incl - tsum);

    if (base + 0 < NN) { offs[base + 0] = run; cursor[base + 0] = run; run += c0; }
    if (base + 1 < NN) { offs[base + 1] = run; cursor[base + 1] = run; run += c1; }
    if (base + 2 < NN) { offs[base + 2] = run; cursor[base + 2] = run; run += c2; }
    if (base + 3 < NN) { offs[base + 3] = run; cursor[base + 3] = run; }
}

__global__ __launch_bounds__(256) void scatter_kernel(
    const int* __restrict__ esrc, const int* __restrict__ etgt,
    int* __restrict__ cursor, int* __restrict__ ssrc)
{
    int e = blockIdx.x * 256 + threadIdx.x;
    if (e < NE) {
        int t = etgt[e];
        int p = atomicAdd(&cursor[t], 1);
        ssrc[p] = esrc[e];
    }
}

// ---------------------------------------------------------------------------
// Gather kernel: one 64-lane wave per node, lane = h*16+c.
// Ping-pong 4+4 value pipeline (prefetch distance 8) + decoupled index
// double-buffer (prefetch distance 16). Clamped tail loads hit L1.
// ---------------------------------------------------------------------------
__device__ __forceinline__ float ldv(const unsigned short* __restrict__ vb,
                                     int src, int lane) {
    return bf2f(vb[(size_t)src * 64 + lane]);
}

__global__ __launch_bounds__(256) void gather_kernel(
    const unsigned short* __restrict__ qb, const unsigned short* __restrict__ vb,
    const float* __restrict__ ak,   // [16][4] row-major: ak[c*4+h]
    const int* __restrict__ offs, const int* __restrict__ ssrc,
    float* __restrict__ out)
{
    const int node = (blockIdx.x * 256 + threadIdx.x) >> 6;
    const int lane = threadIdx.x & 63;
    if (node >= NN) return;
    const int h = lane >> 4;
    const int c = lane & 15;
    const float akl = ak[c * 4 + h];
    const int start = offs[node];
    const int end   = offs[node + 1];
    const size_t obase = (size_t)node * 64 + lane;
    if (start >= end) { out[obase] = 0.0f; return; }
    const float qv = bf2f(qb[obase]);

    float vA[4], vB[4];
    int   iA[4], iB[4];
    #pragma unroll
    for (int i = 0; i < 4; i++) {
        int pp = start + i;     pp = pp < end ? pp : start;
        vA[i] = ldv(vb, ssrc[pp], lane);
    }
    #pragma unroll
    for (int i = 0; i < 4; i++) {
        int pp = start + 4 + i; pp = pp < end ? pp : start;
        vB[i] = ldv(vb, ssrc[pp], lane);
    }
    #pragma unroll
    for (int i = 0; i < 4; i++) {
        int pp = start + 8 + i;  pp = pp < end ? pp : start;  iA[i] = ssrc[pp];
        int pq = start + 12 + i; pq = pq < end ? pq : start;  iB[i] = ssrc[pq];
    }

    float accA = 0.f, accB = 0.f, wsA = 0.f, wsB = 0.f;

    for (int p = start; p < end; p += 8) {
        #pragma unroll
        for (int i = 0; i < 4; i++) {
            float a = vA[i];
            float f = qv + a;
            f = fmaxf(f, ALPHA * f);          // leaky_relu
            float x = red16(f * akl);
            float w = (p + i < end) ? __expf(x) : 0.f;
            wsA  += w;
            accA += w * a;
        }
        #pragma unroll
        for (int i = 0; i < 4; i++) vA[i] = ldv(vb, iA[i], lane);   // edges p+8..p+11
        #pragma unroll
        for (int i = 0; i < 4; i++) {
            int pp = p + 16 + i; pp = pp < end ? pp : start; iA[i] = ssrc[pp];
        }
        #pragma unroll
        for (int i = 0; i < 4; i++) {
            float a = vB[i];
            float f = qv + a;
            f = fmaxf(f, ALPHA * f);
            float x = red16(f * akl);
            float w = (p + 4 + i < end) ? __expf(x) : 0.f;
            wsB  += w;
            accB += w * a;
        }
        #pragma unroll
        for (int i = 0; i < 4; i++) vB[i] = ldv(vb, iB[i], lane);   // edges p+12..p+15
        #pragma unroll
        for (int i = 0; i < 4; i++) {
            int pp = p + 20 + i; pp = pp < end ? pp : start; iB[i] = ssrc[pp];
        }
    }

    float wsum = wsA + wsB;
    if (wsum <= 0.f) wsum = 1.f;
    float r = (accA + accB) / wsum;
    out[obase] = r > 0.f ? r : ALPHA * r;
}

extern "C" void kernel_launch(void* const* d_in, const int* in_sizes, int n_in,
                              void* d_out, int out_size, void* d_ws, size_t ws_size,
                              hipStream_t stream) {
    const float* nf   = (const float*)d_in[0];
    const float* Wq   = (const float*)d_in[1];
    const float* bq   = (const float*)d_in[2];
    const float* Wv   = (const float*)d_in[3];
    const float* bv   = (const float*)d_in[4];
    const float* ak   = (const float*)d_in[5];
    const int*   esrc = (const int*)d_in[6];
    const int*   etgt = (const int*)d_in[7];
    float* out = (float*)d_out;

    // workspace layout:
    //   qbf:    NN*64 u16  (12.8 MB)
    //   vbf:    NN*64 u16  (12.8 MB)
    //   cnt:    NN    i32
    //   offs:   NN+1  i32
    //   cursor: NN    i32
    //   ssrc:   NE    i32
    //   bsum:   NBLK  i32
    unsigned short* qbf    = (unsigned short*)d_ws;
    unsigned short* vbf    = qbf + (size_t)NN * 64;
    int*            cnt    = (int*)(vbf + (size_t)NN * 64);
    int*            offs   = cnt + NN;
    int*            cursor = offs + (NN + 1);
    int*            ssrc   = cursor + NN;
    int*            bsum   = ssrc + NE;

    hipMemsetAsync(cnt, 0, (size_t)NN * sizeof(int), stream);

    transform_kernel<<<1024, 256, 0, stream>>>(nf, Wq, bq, Wv, bv, qbf, vbf);
    hist_kernel<<<(NE + 255) / 256, 256, 0, stream>>>(etgt, cnt);
    scan_partial_kernel<<<NBLK, 256, 0, stream>>>(cnt, bsum);
    scan_bsums_kernel<<<1, 128, 0, stream>>>(bsum, offs);
    scan_final_kernel<<<NBLK, 256, 0, stream>>>(cnt, bsum, offs, cursor);
    scatter_kernel<<<(NE + 255) / 256, 256, 0, stream>>>(esrc, etgt, cursor, ssrc);
    gather_kernel<<<(NN * 64 + 255) / 256, 256, 0, stream>>>(qbf, vbf, ak, offs, ssrc, out);
}

// Round 6
// 199.052 us; speedup vs baseline: 2.0485x; 1.7397x over previous
//
#include <hip/hip_runtime.h>

#define NN 100000
#define NE 1600000
#define ALPHA 0.2f

#define BSH   9                          // 512 nodes per bucket
#define NPBK  512                        // nodes per bucket
#define NBUCK ((NN + NPBK - 1) / NPBK)   // 196 buckets
#define NPB   256                        // partition blocks
#define CHUNK ((NE + NPB - 1) / NPB)     // 6250 edges per block

// ---------------- bf16 helpers (RNE pack, cheap unpack) ---------------------
__device__ __forceinline__ unsigned short f2bf(float f) {
    unsigned int u = __builtin_bit_cast(unsigned int, f);
    u += 0x7FFFu + ((u >> 16) & 1u);
    return (unsigned short)(u >> 16);
}
__device__ __forceinline__ float bf2f(unsigned short u) {
    return __builtin_bit_cast(float, (unsigned int)u << 16);
}

// ---------------- DPP 16-lane sum (all VALU, no DS pipe) --------------------
template<int CTRL>
__device__ __forceinline__ float dpp_add(float x) {
    int y = __builtin_amdgcn_update_dpp(0, __builtin_bit_cast(int, x),
                                        CTRL, 0xF, 0xF, true);
    return x + __builtin_bit_cast(float, y);
}
__device__ __forceinline__ float red16(float x) {
    x = dpp_add<0xB1>(x);    // quad_perm(1,0,3,2)  : xor 1
    x = dpp_add<0x4E>(x);    // quad_perm(2,3,0,1)  : xor 2
    x = dpp_add<0x141>(x);   // row_half_mirror
    x = dpp_add<0x140>(x);   // row_mirror
    return x;
}

// ---------------- 256-thread block exclusive scan ---------------------------
__device__ __forceinline__ int block_excl_scan_256(int val, int* lds4) {
    const int lane = threadIdx.x & 63;
    const int wid  = threadIdx.x >> 6;
    int incl = val;
    #pragma unroll
    for (int off = 1; off < 64; off <<= 1) {
        int t = __shfl_up(incl, off);
        if (lane >= off) incl += t;
    }
    if (lane == 63) lds4[wid] = incl;
    __syncthreads();
    int wbase = 0;
    #pragma unroll
    for (int w = 0; w < 4; w++) if (w < wid) wbase += lds4[w];
    __syncthreads();
    return wbase + incl - val;
}

// ---------------------------------------------------------------------------
// Kernel 1: node transform  Qb = bf16(nf@Wq + bq), Vb = bf16(nf@Wv + bv)
// ---------------------------------------------------------------------------
__global__ __launch_bounds__(256) void transform_kernel(
    const float* __restrict__ nf, const float* __restrict__ Wq, const float* __restrict__ bq,
    const float* __restrict__ Wv, const float* __restrict__ bv,
    unsigned short* __restrict__ qbf, unsigned short* __restrict__ vbf)
{
    __shared__ float sWq[64][64];
    __shared__ float sWv[64][64];
    __shared__ float sX[16][64];
    for (int i = threadIdx.x; i < 4096; i += 256) {
        sWq[i >> 6][i & 63] = Wq[i];
        sWv[i >> 6][i & 63] = Wv[i];
    }
    const int j  = threadIdx.x & 63;
    const int r0 = threadIdx.x >> 6;
    const float bqj = bq[j], bvj = bv[j];
    __syncthreads();

    const int ngroups = (NN + 15) >> 4;
    for (int g = blockIdx.x; g < ngroups; g += gridDim.x) {
        const int base = g << 4;
        #pragma unroll
        for (int i = 0; i < 4; i++) {
            int idx = threadIdx.x + i * 256;
            int row = base + (idx >> 6);
            sX[idx >> 6][idx & 63] = (row < NN) ? nf[(size_t)row * 64 + (idx & 63)] : 0.0f;
        }
        __syncthreads();

        float aq0 = bqj, aq1 = bqj, aq2 = bqj, aq3 = bqj;
        float av0 = bvj, av1 = bvj, av2 = bvj, av3 = bvj;
        #pragma unroll 8
        for (int k = 0; k < 64; k++) {
            float wq = sWq[k][j], wv = sWv[k][j];
            float x0 = sX[r0 * 4 + 0][k];
            float x1 = sX[r0 * 4 + 1][k];
            float x2 = sX[r0 * 4 + 2][k];
            float x3 = sX[r0 * 4 + 3][k];
            aq0 += x0 * wq; av0 += x0 * wv;
            aq1 += x1 * wq; av1 += x1 * wv;
            aq2 += x2 * wq; av2 += x2 * wv;
            aq3 += x3 * wq; av3 += x3 * wv;
        }
        const int row = base + r0 * 4;
        float aqs[4] = {aq0, aq1, aq2, aq3};
        float avs[4] = {av0, av1, av2, av3};
        #pragma unroll
        for (int i = 0; i < 4; i++)
            if (row + i < NN) {
                qbf[(size_t)(row + i) * 64 + j] = f2bf(aqs[i]);
                vbf[(size_t)(row + i) * 64 + j] = f2bf(avs[i]);
            }
        __syncthreads();
    }
}

// ---------------------------------------------------------------------------
// CSR build v2: bucketed counting sort, all position-atomics in LDS.
// ---------------------------------------------------------------------------
// K1: per-block LDS histogram over buckets
__global__ __launch_bounds__(256) void bucket_count_kernel(
    const int* __restrict__ etgt, int* __restrict__ hist, int* __restrict__ gtotal)
{
    __shared__ int h[NBUCK];
    for (int i = threadIdx.x; i < NBUCK; i += 256) h[i] = 0;
    __syncthreads();
    const int blk = blockIdx.x;
    const int e0 = blk * CHUNK;
    const int e1 = min(e0 + CHUNK, NE);
    for (int e = e0 + threadIdx.x; e < e1; e += 256)
        atomicAdd(&h[etgt[e] >> BSH], 1);
    __syncthreads();
    for (int i = threadIdx.x; i < NBUCK; i += 256) {
        int c = h[i];
        hist[blk * NBUCK + i] = c;
        if (c) atomicAdd(&gtotal[i], c);
    }
}

// K2: exclusive scan of bucket totals -> bbase[0..NBUCK]; offs[NN]=NE
__global__ __launch_bounds__(256) void base_scan_kernel(
    const int* __restrict__ gtotal, int* __restrict__ bbase, int* __restrict__ offs)
{
    __shared__ int lds4[4];
    int val = (threadIdx.x < NBUCK) ? gtotal[threadIdx.x] : 0;
    int ex = block_excl_scan_256(val, lds4);
    if (threadIdx.x <= NBUCK) bbase[threadIdx.x] = ex;  // ex at NBUCK == NE
    if (threadIdx.x == 0) offs[NN] = NE;
}

// K3: per-bucket scan across blocks -> colbase[blk][bk]
__global__ __launch_bounds__(256) void colbase_kernel(
    const int* __restrict__ hist, const int* __restrict__ bbase, int* __restrict__ colbase)
{
    __shared__ int lds4[4];
    const int bk = blockIdx.x;
    int val = hist[threadIdx.x * NBUCK + bk];
    int ex = block_excl_scan_256(val, lds4);
    colbase[threadIdx.x * NBUCK + bk] = bbase[bk] + ex;
}

// K4: partition edges into bucket-ordered packed array.
// Each block's writes per bucket land in a private contiguous run.
__global__ __launch_bounds__(256) void partition_kernel(
    const int* __restrict__ esrc, const int* __restrict__ etgt,
    const int* __restrict__ colbase, unsigned int* __restrict__ packed)
{
    __shared__ int cur[NBUCK];
    const int blk = blockIdx.x;
    for (int i = threadIdx.x; i < NBUCK; i += 256)
        cur[i] = colbase[blk * NBUCK + i];
    __syncthreads();
    const int e0 = blk * CHUNK;
    const int e1 = min(e0 + CHUNK, NE);
    for (int e = e0 + threadIdx.x; e < e1; e += 256) {
        int t = etgt[e], s = esrc[e];
        int bk = t >> BSH;
        int pos = atomicAdd(&cur[bk], 1);
        packed[pos] = (unsigned)s | ((unsigned)(t & (NPBK - 1)) << 17);
    }
}

// K5: per-bucket LDS counting sort -> offs + ssrc (writes confined to
// the bucket's ~32KB window, L2-resident).
__global__ __launch_bounds__(256) void bucket_csr_kernel(
    const unsigned int* __restrict__ packed, const int* __restrict__ bbase,
    int* __restrict__ offs, int* __restrict__ ssrc)
{
    __shared__ int cnt[NPBK];
    __shared__ int loff[NPBK];
    __shared__ int lds4[4];
    const int bk = blockIdx.x;
    const int s0 = bbase[bk], s1 = bbase[bk + 1];
    for (int i = threadIdx.x; i < NPBK; i += 256) cnt[i] = 0;
    __syncthreads();
    for (int e = s0 + threadIdx.x; e < s1; e += 256)
        atomicAdd(&cnt[packed[e] >> 17], 1);
    __syncthreads();
    int a0 = cnt[2 * threadIdx.x], a1 = cnt[2 * threadIdx.x + 1];
    int ex = block_excl_scan_256(a0 + a1, lds4);
    loff[2 * threadIdx.x]     = ex;
    loff[2 * threadIdx.x + 1] = ex + a0;
    __syncthreads();
    for (int i = threadIdx.x; i < NPBK; i += 256) {
        int node = (bk << BSH) + i;
        int g = s0 + loff[i];
        if (node < NN) offs[node] = g;
        cnt[i] = g;                      // becomes cursor
    }
    __syncthreads();
    for (int e = s0 + threadIdx.x; e < s1; e += 256) {
        unsigned p = packed[e];
        int tl  = p >> 17;
        int pos = atomicAdd(&cnt[tl], 1);
        ssrc[pos] = (int)(p & 0x1FFFFu);
    }
}

// ---------------------------------------------------------------------------
// Gather kernel: one 64-lane wave per node, lane = h*16+c.
// Ping-pong 4+4 value pipeline + decoupled index double-buffer.
// ---------------------------------------------------------------------------
__device__ __forceinline__ float ldv(const unsigned short* __restrict__ vb,
                                     int src, int lane) {
    return bf2f(vb[(size_t)src * 64 + lane]);
}

__global__ __launch_bounds__(256) void gather_kernel(
    const unsigned short* __restrict__ qb, const unsigned short* __restrict__ vb,
    const float* __restrict__ ak,   // [16][4] row-major: ak[c*4+h]
    const int* __restrict__ offs, const int* __restrict__ ssrc,
    float* __restrict__ out)
{
    const int node = (blockIdx.x * 256 + threadIdx.x) >> 6;
    const int lane = threadIdx.x & 63;
    if (node >= NN) return;
    const int h = lane >> 4;
    const int c = lane & 15;
    const float akl = ak[c * 4 + h];
    const int start = offs[node];
    const int end   = offs[node + 1];
    const size_t obase = (size_t)node * 64 + lane;
    if (start >= end) { out[obase] = 0.0f; return; }
    const float qv = bf2f(qb[obase]);

    float vA[4], vB[4];
    int   iA[4], iB[4];
    #pragma unroll
    for (int i = 0; i < 4; i++) {
        int pp = start + i;     pp = pp < end ? pp : start;
        vA[i] = ldv(vb, ssrc[pp], lane);
    }
    #pragma unroll
    for (int i = 0; i < 4; i++) {
        int pp = start + 4 + i; pp = pp < end ? pp : start;
        vB[i] = ldv(vb, ssrc[pp], lane);
    }
    #pragma unroll
    for (int i = 0; i < 4; i++) {
        int pp = start + 8 + i;  pp = pp < end ? pp : start;  iA[i] = ssrc[pp];
        int pq = start + 12 + i; pq = pq < end ? pq : start;  iB[i] = ssrc[pq];
    }

    float accA = 0.f, accB = 0.f, wsA = 0.f, wsB = 0.f;

    for (int p = start; p < end; p += 8) {
        #pragma unroll
        for (int i = 0; i < 4; i++) {
            float a = vA[i];
            float f = qv + a;
            f = fmaxf(f, ALPHA * f);
            float x = red16(f * akl);
            float w = (p + i < end) ? __expf(x) : 0.f;
            wsA  += w;
            accA += w * a;
        }
        #pragma unroll
        for (int i = 0; i < 4; i++) vA[i] = ldv(vb, iA[i], lane);
        #pragma unroll
        for (int i = 0; i < 4; i++) {
            int pp = p + 16 + i; pp = pp < end ? pp : start; iA[i] = ssrc[pp];
        }
        #pragma unroll
        for (int i = 0; i < 4; i++) {
            float a = vB[i];
            float f = qv + a;
            f = fmaxf(f, ALPHA * f);
            float x = red16(f * akl);
            float w = (p + 4 + i < end) ? __expf(x) : 0.f;
            wsB  += w;
            accB += w * a;
        }
        #pragma unroll
        for (int i = 0; i < 4; i++) vB[i] = ldv(vb, iB[i], lane);
        #pragma unroll
        for (int i = 0; i < 4; i++) {
            int pp = p + 20 + i; pp = pp < end ? pp : start; iB[i] = ssrc[pp];
        }
    }

    float wsum = wsA + wsB;
    if (wsum <= 0.f) wsum = 1.f;
    float r = (accA + accB) / wsum;
    out[obase] = r > 0.f ? r : ALPHA * r;
}

extern "C" void kernel_launch(void* const* d_in, const int* in_sizes, int n_in,
                              void* d_out, int out_size, void* d_ws, size_t ws_size,
                              hipStream_t stream) {
    const float* nf   = (const float*)d_in[0];
    const float* Wq   = (const float*)d_in[1];
    const float* bq   = (const float*)d_in[2];
    const float* Wv   = (const float*)d_in[3];
    const float* bv   = (const float*)d_in[4];
    const float* ak   = (const float*)d_in[5];
    const int*   esrc = (const int*)d_in[6];
    const int*   etgt = (const int*)d_in[7];
    float* out = (float*)d_out;

    // workspace layout:
    //   qbf:     NN*64      u16  (12.8 MB)
    //   vbf:     NN*64      u16  (12.8 MB)
    //   offs:    NN+1       i32
    //   ssrc:    NE         i32  (6.4 MB)
    //   packed:  NE         u32  (6.4 MB)
    //   hist:    NPB*NBUCK  i32  (200 KB)
    //   colbase: NPB*NBUCK  i32  (200 KB)
    //   gtotal:  NBUCK      i32
    //   bbase:   NBUCK+1    i32
    unsigned short* qbf     = (unsigned short*)d_ws;
    unsigned short* vbf     = qbf + (size_t)NN * 64;
    int*            offs    = (int*)(vbf + (size_t)NN * 64);
    int*            ssrc    = offs + (NN + 1);
    unsigned int*   packed  = (unsigned int*)(ssrc + NE);
    int*            hist    = (int*)(packed + NE);
    int*            colbase = hist + NPB * NBUCK;
    int*            gtotal  = colbase + NPB * NBUCK;
    int*            bbase   = gtotal + NBUCK;

    hipMemsetAsync(gtotal, 0, NBUCK * sizeof(int), stream);

    transform_kernel<<<1024, 256, 0, stream>>>(nf, Wq, bq, Wv, bv, qbf, vbf);
    bucket_count_kernel<<<NPB, 256, 0, stream>>>(etgt, hist, gtotal);
    base_scan_kernel<<<1, 256, 0, stream>>>(gtotal, bbase, offs);
    colbase_kernel<<<NBUCK, 256, 0, stream>>>(hist, bbase, colbase);
    partition_kernel<<<NPB, 256, 0, stream>>>(esrc, etgt, colbase, packed);
    bucket_csr_kernel<<<NBUCK, 256, 0, stream>>>(packed, bbase, offs, ssrc);
    gather_kernel<<<(NN * 64 + 255) / 256, 256, 0, stream>>>(qbf, vbf, ak, offs, ssrc, out);
}

// Round 7
// 166.283 us; speedup vs baseline: 2.4523x; 1.1971x over previous
//
#include <hip/hip_runtime.h>

#define NN 100000
#define NE 1600000
#define ALPHA 0.2f

#define BSH   9                          // 512 nodes per bucket
#define NPBK  512                        // nodes per bucket
#define NBUCK ((NN + NPBK - 1) / NPBK)   // 196 buckets
#define NPB   256                        // partition blocks
#define CHUNK ((NE + NPB - 1) / NPB)     // 6250 edges per block

// ---------------- bf16 helpers (RNE pack, cheap unpack) ---------------------
__device__ __forceinline__ unsigned short f2bf(float f) {
    unsigned int u = __builtin_bit_cast(unsigned int, f);
    u += 0x7FFFu + ((u >> 16) & 1u);
    return (unsigned short)(u >> 16);
}
__device__ __forceinline__ float bflo(unsigned int u) {
    return __builtin_bit_cast(float, u << 16);
}
__device__ __forceinline__ float bfhi(unsigned int u) {
    return __builtin_bit_cast(float, u & 0xFFFF0000u);
}

// ---------------- DPP adds (all VALU, no DS pipe) ---------------------------
template<int CTRL>
__device__ __forceinline__ float dpp_add(float x) {
    int y = __builtin_amdgcn_update_dpp(0, __builtin_bit_cast(int, x),
                                        CTRL, 0xF, 0xF, true);
    return x + __builtin_bit_cast(float, y);
}

// ---------------- 256-thread block exclusive scan ---------------------------
__device__ __forceinline__ int block_excl_scan_256(int val, int* lds4) {
    const int lane = threadIdx.x & 63;
    const int wid  = threadIdx.x >> 6;
    int incl = val;
    #pragma unroll
    for (int off = 1; off < 64; off <<= 1) {
        int t = __shfl_up(incl, off);
        if (lane >= off) incl += t;
    }
    if (lane == 63) lds4[wid] = incl;
    __syncthreads();
    int wbase = 0;
    #pragma unroll
    for (int w = 0; w < 4; w++) if (w < wid) wbase += lds4[w];
    __syncthreads();
    return wbase + incl - val;
}

// ---------------------------------------------------------------------------
// Kernel 1: node transform  Qb = bf16(nf@Wq + bq), Vb = bf16(nf@Wv + bv)
// ---------------------------------------------------------------------------
__global__ __launch_bounds__(256) void transform_kernel(
    const float* __restrict__ nf, const float* __restrict__ Wq, const float* __restrict__ bq,
    const float* __restrict__ Wv, const float* __restrict__ bv,
    unsigned short* __restrict__ qbf, unsigned short* __restrict__ vbf)
{
    __shared__ float sWq[64][64];
    __shared__ float sWv[64][64];
    __shared__ float sX[16][64];
    for (int i = threadIdx.x; i < 4096; i += 256) {
        sWq[i >> 6][i & 63] = Wq[i];
        sWv[i >> 6][i & 63] = Wv[i];
    }
    const int j  = threadIdx.x & 63;
    const int r0 = threadIdx.x >> 6;
    const float bqj = bq[j], bvj = bv[j];
    __syncthreads();

    const int ngroups = (NN + 15) >> 4;
    for (int g = blockIdx.x; g < ngroups; g += gridDim.x) {
        const int base = g << 4;
        #pragma unroll
        for (int i = 0; i < 4; i++) {
            int idx = threadIdx.x + i * 256;
            int row = base + (idx >> 6);
            sX[idx >> 6][idx & 63] = (row < NN) ? nf[(size_t)row * 64 + (idx & 63)] : 0.0f;
        }
        __syncthreads();

        float aq0 = bqj, aq1 = bqj, aq2 = bqj, aq3 = bqj;
        float av0 = bvj, av1 = bvj, av2 = bvj, av3 = bvj;
        #pragma unroll 8
        for (int k = 0; k < 64; k++) {
            float wq = sWq[k][j], wv = sWv[k][j];
            float x0 = sX[r0 * 4 + 0][k];
            float x1 = sX[r0 * 4 + 1][k];
            float x2 = sX[r0 * 4 + 2][k];
            float x3 = sX[r0 * 4 + 3][k];
            aq0 += x0 * wq; av0 += x0 * wv;
            aq1 += x1 * wq; av1 += x1 * wv;
            aq2 += x2 * wq; av2 += x2 * wv;
            aq3 += x3 * wq; av3 += x3 * wv;
        }
        const int row = base + r0 * 4;
        float aqs[4] = {aq0, aq1, aq2, aq3};
        float avs[4] = {av0, av1, av2, av3};
        #pragma unroll
        for (int i = 0; i < 4; i++)
            if (row + i < NN) {
                qbf[(size_t)(row + i) * 64 + j] = f2bf(aqs[i]);
                vbf[(size_t)(row + i) * 64 + j] = f2bf(avs[i]);
            }
        __syncthreads();
    }
}

// ---------------------------------------------------------------------------
// CSR build v2: bucketed counting sort, all position-atomics in LDS.
// ---------------------------------------------------------------------------
__global__ __launch_bounds__(256) void bucket_count_kernel(
    const int* __restrict__ etgt, int* __restrict__ hist, int* __restrict__ gtotal)
{
    __shared__ int h[NBUCK];
    for (int i = threadIdx.x; i < NBUCK; i += 256) h[i] = 0;
    __syncthreads();
    const int blk = blockIdx.x;
    const int e0 = blk * CHUNK;
    const int e1 = min(e0 + CHUNK, NE);
    for (int e = e0 + threadIdx.x; e < e1; e += 256)
        atomicAdd(&h[etgt[e] >> BSH], 1);
    __syncthreads();
    for (int i = threadIdx.x; i < NBUCK; i += 256) {
        int c = h[i];
        hist[blk * NBUCK + i] = c;
        if (c) atomicAdd(&gtotal[i], c);
    }
}

__global__ __launch_bounds__(256) void base_scan_kernel(
    const int* __restrict__ gtotal, int* __restrict__ bbase, int* __restrict__ offs)
{
    __shared__ int lds4[4];
    int val = (threadIdx.x < NBUCK) ? gtotal[threadIdx.x] : 0;
    int ex = block_excl_scan_256(val, lds4);
    if (threadIdx.x <= NBUCK) bbase[threadIdx.x] = ex;  // ex at NBUCK == NE
    if (threadIdx.x == 0) offs[NN] = NE;
}

__global__ __launch_bounds__(256) void colbase_kernel(
    const int* __restrict__ hist, const int* __restrict__ bbase, int* __restrict__ colbase)
{
    __shared__ int lds4[4];
    const int bk = blockIdx.x;
    int val = hist[threadIdx.x * NBUCK + bk];
    int ex = block_excl_scan_256(val, lds4);
    colbase[threadIdx.x * NBUCK + bk] = bbase[bk] + ex;
}

__global__ __launch_bounds__(256) void partition_kernel(
    const int* __restrict__ esrc, const int* __restrict__ etgt,
    const int* __restrict__ colbase, unsigned int* __restrict__ packed)
{
    __shared__ int cur[NBUCK];
    const int blk = blockIdx.x;
    for (int i = threadIdx.x; i < NBUCK; i += 256)
        cur[i] = colbase[blk * NBUCK + i];
    __syncthreads();
    const int e0 = blk * CHUNK;
    const int e1 = min(e0 + CHUNK, NE);
    for (int e = e0 + threadIdx.x; e < e1; e += 256) {
        int t = etgt[e], s = esrc[e];
        int bk = t >> BSH;
        int pos = atomicAdd(&cur[bk], 1);
        packed[pos] = (unsigned)s | ((unsigned)(t & (NPBK - 1)) << 17);
    }
}

__global__ __launch_bounds__(256) void bucket_csr_kernel(
    const unsigned int* __restrict__ packed, const int* __restrict__ bbase,
    int* __restrict__ offs, int* __restrict__ ssrc)
{
    __shared__ int cnt[NPBK];
    __shared__ int loff[NPBK];
    __shared__ int lds4[4];
    const int bk = blockIdx.x;
    const int s0 = bbase[bk], s1 = bbase[bk + 1];
    for (int i = threadIdx.x; i < NPBK; i += 256) cnt[i] = 0;
    __syncthreads();
    for (int e = s0 + threadIdx.x; e < s1; e += 256)
        atomicAdd(&cnt[packed[e] >> 17], 1);
    __syncthreads();
    int a0 = cnt[2 * threadIdx.x], a1 = cnt[2 * threadIdx.x + 1];
    int ex = block_excl_scan_256(a0 + a1, lds4);
    loff[2 * threadIdx.x]     = ex;
    loff[2 * threadIdx.x + 1] = ex + a0;
    __syncthreads();
    for (int i = threadIdx.x; i < NPBK; i += 256) {
        int node = (bk << BSH) + i;
        int g = s0 + loff[i];
        if (node < NN) offs[node] = g;
        cnt[i] = g;                      // becomes cursor
    }
    __syncthreads();
    for (int e = s0 + threadIdx.x; e < s1; e += 256) {
        unsigned p = packed[e];
        int tl  = p >> 17;
        int pos = atomicAdd(&cnt[tl], 1);
        ssrc[pos] = (int)(p & 0x1FFFFu);
    }
}

// ---------------------------------------------------------------------------
// Gather kernel v3: one wave per node; 4 edges per wave-iteration.
// lane = edge_slot(2b) * 16 + sub;  sub -> head h=sub>>2, quad cq=sub&3,
// channels ch = sub*4 .. sub*4+3 (dwordx2 = 4 bf16 per lane, 128B per row).
// Head logit reduce = 2 quad-perm DPP adds. Values prefetched 8 edges
// ahead, indices 16 ahead; positions clamped only against NE (masked by w=0).
// ---------------------------------------------------------------------------
__device__ __forceinline__ uint2 ldraw(const unsigned short* __restrict__ vb,
                                       int src, int sub) {
    return *(const uint2*)((const char*)vb + ((size_t)src << 7) + sub * 8);
}

__global__ __launch_bounds__(256) void gather_kernel(
    const unsigned short* __restrict__ qb, const unsigned short* __restrict__ vb,
    const float* __restrict__ ak,   // [16][4] row-major: ak[c*4+h]
    const int* __restrict__ offs, const int* __restrict__ ssrc,
    float* __restrict__ out)
{
    const int node = (blockIdx.x * 256 + threadIdx.x) >> 6;
    const int lane = threadIdx.x & 63;
    if (node >= NN) return;
    const int eidx = lane >> 4;      // edge slot 0..3
    const int sub  = lane & 15;
    const int h    = sub >> 2;
    const int cq   = sub & 3;

    const int start = offs[node];
    const int end   = offs[node + 1];

    if (start >= end) {
        if (lane < 16)
            *(float4*)(out + (size_t)node * 64 + sub * 4) = float4{0.f, 0.f, 0.f, 0.f};
        return;
    }

    const float ak0 = ak[(cq * 4 + 0) * 4 + h];
    const float ak1 = ak[(cq * 4 + 1) * 4 + h];
    const float ak2 = ak[(cq * 4 + 2) * 4 + h];
    const float ak3 = ak[(cq * 4 + 3) * 4 + h];

    uint2 qraw = *(const uint2*)((const char*)qb + ((size_t)node << 7) + sub * 8);
    const float q0 = bflo(qraw.x), q1 = bfhi(qraw.x);
    const float q2 = bflo(qraw.y), q3 = bfhi(qraw.y);

    // pipeline prologue: values for edges start..start+7, indices for +8..+15
    int iA = ssrc[min(start +      eidx, NE - 1)];
    int iB = ssrc[min(start +  4 + eidx, NE - 1)];
    uint2 rA = ldraw(vb, iA, sub);
    uint2 rB = ldraw(vb, iB, sub);
    int nA = ssrc[min(start +  8 + eidx, NE - 1)];
    int nB = ssrc[min(start + 12 + eidx, NE - 1)];

    float a0 = 0.f, a1 = 0.f, a2 = 0.f, a3 = 0.f, ws = 0.f;

    for (int p = start; p < end; p += 8) {
        // ---- half A: edges p+0..p+3 ----
        {
            float v0 = bflo(rA.x), v1 = bfhi(rA.x), v2 = bflo(rA.y), v3 = bfhi(rA.y);
            rA = ldraw(vb, nA, sub);                       // edges p+8..p+11
            nA = ssrc[min(p + 16 + eidx, NE - 1)];         // edges p+16..p+19
            float f0 = q0 + v0, f1 = q1 + v1, f2 = q2 + v2, f3 = q3 + v3;
            f0 = fmaxf(f0, ALPHA * f0); f1 = fmaxf(f1, ALPHA * f1);
            f2 = fmaxf(f2, ALPHA * f2); f3 = fmaxf(f3, ALPHA * f3);
            float x = f0 * ak0;
            x = fmaf(f1, ak1, x); x = fmaf(f2, ak2, x); x = fmaf(f3, ak3, x);
            x = dpp_add<0xB1>(x);    // quad xor1
            x = dpp_add<0x4E>(x);    // quad xor2 -> full head sum
            float w = (p + eidx < end) ? __expf(x) : 0.f;
            ws += w;
            a0 = fmaf(w, v0, a0); a1 = fmaf(w, v1, a1);
            a2 = fmaf(w, v2, a2); a3 = fmaf(w, v3, a3);
        }
        // ---- half B: edges p+4..p+7 ----
        {
            float v0 = bflo(rB.x), v1 = bfhi(rB.x), v2 = bflo(rB.y), v3 = bfhi(rB.y);
            rB = ldraw(vb, nB, sub);                       // edges p+12..p+15
            nB = ssrc[min(p + 20 + eidx, NE - 1)];         // edges p+20..p+23
            float f0 = q0 + v0, f1 = q1 + v1, f2 = q2 + v2, f3 = q3 + v3;
            f0 = fmaxf(f0, ALPHA * f0); f1 = fmaxf(f1, ALPHA * f1);
            f2 = fmaxf(f2, ALPHA * f2); f3 = fmaxf(f3, ALPHA * f3);
            float x = f0 * ak0;
            x = fmaf(f1, ak1, x); x = fmaf(f2, ak2, x); x = fmaf(f3, ak3, x);
            x = dpp_add<0xB1>(x);
            x = dpp_add<0x4E>(x);
            float w = (p + 4 + eidx < end) ? __expf(x) : 0.f;
            ws += w;
            a0 = fmaf(w, v0, a0); a1 = fmaf(w, v1, a1);
            a2 = fmaf(w, v2, a2); a3 = fmaf(w, v3, a3);
        }
    }

    // combine the 4 edge slots (xor16 then xor32)
    a0 += __shfl_xor(a0, 16); a1 += __shfl_xor(a1, 16);
    a2 += __shfl_xor(a2, 16); a3 += __shfl_xor(a3, 16);
    ws += __shfl_xor(ws, 16);
    a0 += __shfl_xor(a0, 32); a1 += __shfl_xor(a1, 32);
    a2 += __shfl_xor(a2, 32); a3 += __shfl_xor(a3, 32);
    ws += __shfl_xor(ws, 32);

    if (lane < 16) {
        float inv = (ws > 0.f) ? __frcp_rn(ws) : 1.0f;
        float r0 = a0 * inv, r1 = a1 * inv, r2 = a2 * inv, r3 = a3 * inv;
        r0 = fmaxf(r0, ALPHA * r0); r1 = fmaxf(r1, ALPHA * r1);
        r2 = fmaxf(r2, ALPHA * r2); r3 = fmaxf(r3, ALPHA * r3);
        *(float4*)(out + (size_t)node * 64 + sub * 4) = float4{r0, r1, r2, r3};
    }
}

extern "C" void kernel_launch(void* const* d_in, const int* in_sizes, int n_in,
                              void* d_out, int out_size, void* d_ws, size_t ws_size,
                              hipStream_t stream) {
    const float* nf   = (const float*)d_in[0];
    const float* Wq   = (const float*)d_in[1];
    const float* bq   = (const float*)d_in[2];
    const float* Wv   = (const float*)d_in[3];
    const float* bv   = (const float*)d_in[4];
    const float* ak   = (const float*)d_in[5];
    const int*   esrc = (const int*)d_in[6];
    const int*   etgt = (const int*)d_in[7];
    float* out = (float*)d_out;

    // workspace layout:
    //   qbf:     NN*64      u16  (12.8 MB)
    //   vbf:     NN*64      u16  (12.8 MB)
    //   offs:    NN+1       i32
    //   ssrc:    NE         i32  (6.4 MB)
    //   packed:  NE         u32  (6.4 MB)
    //   hist:    NPB*NBUCK  i32  (200 KB)
    //   colbase: NPB*NBUCK  i32  (200 KB)
    //   gtotal:  NBUCK      i32
    //   bbase:   NBUCK+1    i32
    unsigned short* qbf     = (unsigned short*)d_ws;
    unsigned short* vbf     = qbf + (size_t)NN * 64;
    int*            offs    = (int*)(vbf + (size_t)NN * 64);
    int*            ssrc    = offs + (NN + 1);
    unsigned int*   packed  = (unsigned int*)(ssrc + NE);
    int*            hist    = (int*)(packed + NE);
    int*            colbase = hist + NPB * NBUCK;
    int*            gtotal  = colbase + NPB * NBUCK;
    int*            bbase   = gtotal + NBUCK;

    hipMemsetAsync(gtotal, 0, NBUCK * sizeof(int), stream);

    transform_kernel<<<1024, 256, 0, stream>>>(nf, Wq, bq, Wv, bv, qbf, vbf);
    bucket_count_kernel<<<NPB, 256, 0, stream>>>(etgt, hist, gtotal);
    base_scan_kernel<<<1, 256, 0, stream>>>(gtotal, bbase, offs);
    colbase_kernel<<<NBUCK, 256, 0, stream>>>(hist, bbase, colbase);
    partition_kernel<<<NPB, 256, 0, stream>>>(esrc, etgt, colbase, packed);
    bucket_csr_kernel<<<NBUCK, 256, 0, stream>>>(packed, bbase, offs, ssrc);
    gather_kernel<<<(NN * 64 + 255) / 256, 256, 0, stream>>>(qbf, vbf, ak, offs, ssrc, out);
}

// Round 8
// 135.674 us; speedup vs baseline: 3.0055x; 1.2256x over previous
//
#include <hip/hip_runtime.h>

#define NN 100000
#define NE 1600000
#define ALPHA 0.2f

#define BSH   9                          // 512 nodes per bucket
#define NPBK  512                        // nodes per bucket
#define NBUCK ((NN + NPBK - 1) / NPBK)   // 196 buckets
#define NPB   256                        // partition blocks
#define CHUNK ((NE + NPB - 1) / NPB)     // 6250 edges per block

#define MTILES (NN / 16)                 // 6250 (NN % 16 == 0)
#define TBLKS  ((MTILES + 3) / 4)        // 1563 transform blocks

typedef __attribute__((ext_vector_type(8))) short  short8;
typedef __attribute__((ext_vector_type(4))) float  f32x4;

// ---------------- bf16 helpers (RNE pack, cheap unpack) ---------------------
__device__ __forceinline__ unsigned short f2bf(float f) {
    unsigned int u = __builtin_bit_cast(unsigned int, f);
    u += 0x7FFFu + ((u >> 16) & 1u);
    return (unsigned short)(u >> 16);
}
__device__ __forceinline__ float bf2fs(unsigned short u) {
    return __builtin_bit_cast(float, (unsigned int)u << 16);
}
__device__ __forceinline__ float bflo(unsigned int u) {
    return __builtin_bit_cast(float, u << 16);
}
__device__ __forceinline__ float bfhi(unsigned int u) {
    return __builtin_bit_cast(float, u & 0xFFFF0000u);
}

// ---------------- DPP adds (all VALU, no DS pipe) ---------------------------
template<int CTRL>
__device__ __forceinline__ float dpp_add(float x) {
    int y = __builtin_amdgcn_update_dpp(0, __builtin_bit_cast(int, x),
                                        CTRL, 0xF, 0xF, true);
    return x + __builtin_bit_cast(float, y);
}

// ---------------- 256-thread block exclusive scan ---------------------------
__device__ __forceinline__ int block_excl_scan_256(int val, int* lds4) {
    const int lane = threadIdx.x & 63;
    const int wid  = threadIdx.x >> 6;
    int incl = val;
    #pragma unroll
    for (int off = 1; off < 64; off <<= 1) {
        int t = __shfl_up(incl, off);
        if (lane >= off) incl += t;
    }
    if (lane == 63) lds4[wid] = incl;
    __syncthreads();
    int wbase = 0;
    #pragma unroll
    for (int w = 0; w < 4; w++) if (w < wid) wbase += lds4[w];
    __syncthreads();
    return wbase + incl - val;
}

// ---------------------------------------------------------------------------
// Kernel 1 (MFMA): Qb = bf16(nf@Wq + bq), Vb = bf16(nf@Wv + bv)
// Split-precision: x=xh+xl, W=Wh+Wl (bf16 RNE + residual);
// acc = xh*Wh + xl*Wh + xh*Wl  (error ~2^-16, fp32-equivalent).
// 4 waves/block, one 16-row M-tile per wave. B fragments prepacked in LDS.
// C/D layout (HW-verified): col = lane&15, row = (lane>>4)*4 + reg.
// ---------------------------------------------------------------------------
__global__ __launch_bounds__(256) void transform_kernel(
    const float* __restrict__ nf, const float* __restrict__ Wq, const float* __restrict__ bq,
    const float* __restrict__ Wv, const float* __restrict__ bv,
    unsigned short* __restrict__ qbf, unsigned short* __restrict__ vbf)
{
    __shared__ short8 sB[2][2][8][64];   // [hilo][kstep][ntile][lane], 32 KB
    __shared__ float  sbias[128];
    const int tid = threadIdx.x;

    if (tid < 64)       sbias[tid] = bq[tid];
    else if (tid < 128) sbias[tid] = bv[tid - 64];

    // Pack B fragments: slot = (kstep, ntile, lane); 4 slots per thread.
    for (int slot = tid; slot < 2 * 8 * 64; slot += 256) {
        const int lane  = slot & 63;
        const int ntile = (slot >> 6) & 7;
        const int kstep = slot >> 9;
        const int j     = ntile * 16 + (lane & 15);
        const int kbase = kstep * 32 + (lane >> 4) * 8;
        const float* W  = (j < 64) ? Wq : Wv;
        const int jj    = j & 63;
        short8 hi, lo;
        #pragma unroll
        for (int r = 0; r < 8; r++) {
            float w = W[(kbase + r) * 64 + jj];
            unsigned short h = f2bf(w);
            lo[r] = (short)f2bf(w - bf2fs(h));
            hi[r] = (short)h;
        }
        sB[0][kstep][ntile][lane] = hi;
        sB[1][kstep][ntile][lane] = lo;
    }
    __syncthreads();

    const int lane  = tid & 63;
    const int wv_   = tid >> 6;
    const int row16 = lane & 15;
    const int kg    = lane >> 4;

    for (int wt = blockIdx.x * 4 + wv_; wt < MTILES; wt += (int)gridDim.x * 4) {
        const int row = wt * 16 + row16;

        // A fragments: 8 contiguous fp32 per (lane, kstep) -> hi/lo bf16x8
        short8 ah[2], al[2];
        #pragma unroll
        for (int s = 0; s < 2; s++) {
            const float* ap = nf + (size_t)row * 64 + s * 32 + kg * 8;
            #pragma unroll
            for (int r = 0; r < 8; r++) {
                float x = ap[r];
                unsigned short h = f2bf(x);
                al[s][r] = (short)f2bf(x - bf2fs(h));
                ah[s][r] = (short)h;
            }
        }

        #pragma unroll
        for (int nt = 0; nt < 8; nt++) {
            f32x4 acc = {0.f, 0.f, 0.f, 0.f};
            #pragma unroll
            for (int s = 0; s < 2; s++) {
                short8 bh = sB[0][s][nt][lane];
                short8 bl = sB[1][s][nt][lane];
                acc = __builtin_amdgcn_mfma_f32_16x16x32_bf16(ah[s], bh, acc, 0, 0, 0);
                acc = __builtin_amdgcn_mfma_f32_16x16x32_bf16(al[s], bh, acc, 0, 0, 0);
                acc = __builtin_amdgcn_mfma_f32_16x16x32_bf16(ah[s], bl, acc, 0, 0, 0);
            }
            const int col = nt * 16 + (lane & 15);
            const float b = sbias[col];
            unsigned short* outp = (col < 64) ? qbf : vbf;
            const int jj    = col & 63;
            const int rbase = wt * 16 + (lane >> 4) * 4;
            #pragma unroll
            for (int r = 0; r < 4; r++)
                outp[(size_t)(rbase + r) * 64 + jj] = f2bf(acc[r] + b);
        }
    }
}

// ---------------------------------------------------------------------------
// CSR build v2: bucketed counting sort, all position-atomics in LDS.
// ---------------------------------------------------------------------------
__global__ __launch_bounds__(256) void bucket_count_kernel(
    const int* __restrict__ etgt, int* __restrict__ hist, int* __restrict__ gtotal)
{
    __shared__ int h[NBUCK];
    for (int i = threadIdx.x; i < NBUCK; i += 256) h[i] = 0;
    __syncthreads();
    const int blk = blockIdx.x;
    const int e0 = blk * CHUNK;
    const int e1 = min(e0 + CHUNK, NE);
    for (int e = e0 + threadIdx.x; e < e1; e += 256)
        atomicAdd(&h[etgt[e] >> BSH], 1);
    __syncthreads();
    for (int i = threadIdx.x; i < NBUCK; i += 256) {
        int c = h[i];
        hist[blk * NBUCK + i] = c;
        if (c) atomicAdd(&gtotal[i], c);
    }
}

__global__ __launch_bounds__(256) void base_scan_kernel(
    const int* __restrict__ gtotal, int* __restrict__ bbase, int* __restrict__ offs)
{
    __shared__ int lds4[4];
    int val = (threadIdx.x < NBUCK) ? gtotal[threadIdx.x] : 0;
    int ex = block_excl_scan_256(val, lds4);
    if (threadIdx.x <= NBUCK) bbase[threadIdx.x] = ex;  // ex at NBUCK == NE
    if (threadIdx.x == 0) offs[NN] = NE;
}

__global__ __launch_bounds__(256) void colbase_kernel(
    const int* __restrict__ hist, const int* __restrict__ bbase, int* __restrict__ colbase)
{
    __shared__ int lds4[4];
    const int bk = blockIdx.x;
    int val = hist[threadIdx.x * NBUCK + bk];
    int ex = block_excl_scan_256(val, lds4);
    colbase[threadIdx.x * NBUCK + bk] = bbase[bk] + ex;
}

__global__ __launch_bounds__(256) void partition_kernel(
    const int* __restrict__ esrc, const int* __restrict__ etgt,
    const int* __restrict__ colbase, unsigned int* __restrict__ packed)
{
    __shared__ int cur[NBUCK];
    const int blk = blockIdx.x;
    for (int i = threadIdx.x; i < NBUCK; i += 256)
        cur[i] = colbase[blk * NBUCK + i];
    __syncthreads();
    const int e0 = blk * CHUNK;
    const int e1 = min(e0 + CHUNK, NE);
    for (int e = e0 + threadIdx.x; e < e1; e += 256) {
        int t = etgt[e], s = esrc[e];
        int bk = t >> BSH;
        int pos = atomicAdd(&cur[bk], 1);
        packed[pos] = (unsigned)s | ((unsigned)(t & (NPBK - 1)) << 17);
    }
}

__global__ __launch_bounds__(256) void bucket_csr_kernel(
    const unsigned int* __restrict__ packed, const int* __restrict__ bbase,
    int* __restrict__ offs, int* __restrict__ ssrc)
{
    __shared__ int cnt[NPBK];
    __shared__ int loff[NPBK];
    __shared__ int lds4[4];
    const int bk = blockIdx.x;
    const int s0 = bbase[bk], s1 = bbase[bk + 1];
    for (int i = threadIdx.x; i < NPBK; i += 256) cnt[i] = 0;
    __syncthreads();
    for (int e = s0 + threadIdx.x; e < s1; e += 256)
        atomicAdd(&cnt[packed[e] >> 17], 1);
    __syncthreads();
    int a0 = cnt[2 * threadIdx.x], a1 = cnt[2 * threadIdx.x + 1];
    int ex = block_excl_scan_256(a0 + a1, lds4);
    loff[2 * threadIdx.x]     = ex;
    loff[2 * threadIdx.x + 1] = ex + a0;
    __syncthreads();
    for (int i = threadIdx.x; i < NPBK; i += 256) {
        int node = (bk << BSH) + i;
        int g = s0 + loff[i];
        if (node < NN) offs[node] = g;
        cnt[i] = g;                      // becomes cursor
    }
    __syncthreads();
    for (int e = s0 + threadIdx.x; e < s1; e += 256) {
        unsigned p = packed[e];
        int tl  = p >> 17;
        int pos = atomicAdd(&cnt[tl], 1);
        ssrc[pos] = (int)(p & 0x1FFFFu);
    }
}

// ---------------------------------------------------------------------------
// Gather kernel v3: one wave per node; 4 edges per wave-iteration.
// lane = edge_slot(2b) * 16 + sub;  sub -> head h=sub>>2, quad cq=sub&3,
// channels ch = sub*4 .. sub*4+3 (dwordx2 = 4 bf16 per lane, 128B per row).
// Head logit reduce = 2 quad-perm DPP adds. Values prefetched 8 edges
// ahead, indices 16 ahead; positions clamped only against NE (masked by w=0).
// ---------------------------------------------------------------------------
__device__ __forceinline__ uint2 ldraw(const unsigned short* __restrict__ vb,
                                       int src, int sub) {
    return *(const uint2*)((const char*)vb + ((size_t)src << 7) + sub * 8);
}

__global__ __launch_bounds__(256) void gather_kernel(
    const unsigned short* __restrict__ qb, const unsigned short* __restrict__ vb,
    const float* __restrict__ ak,   // [16][4] row-major: ak[c*4+h]
    const int* __restrict__ offs, const int* __restrict__ ssrc,
    float* __restrict__ out)
{
    const int node = (blockIdx.x * 256 + threadIdx.x) >> 6;
    const int lane = threadIdx.x & 63;
    if (node >= NN) return;
    const int eidx = lane >> 4;      // edge slot 0..3
    const int sub  = lane & 15;
    const int h    = sub >> 2;
    const int cq   = sub & 3;

    const int start = offs[node];
    const int end   = offs[node + 1];

    if (start >= end) {
        if (lane < 16)
            *(float4*)(out + (size_t)node * 64 + sub * 4) = float4{0.f, 0.f, 0.f, 0.f};
        return;
    }

    const float ak0 = ak[(cq * 4 + 0) * 4 + h];
    const float ak1 = ak[(cq * 4 + 1) * 4 + h];
    const float ak2 = ak[(cq * 4 + 2) * 4 + h];
    const float ak3 = ak[(cq * 4 + 3) * 4 + h];

    uint2 qraw = *(const uint2*)((const char*)qb + ((size_t)node << 7) + sub * 8);
    const float q0 = bflo(qraw.x), q1 = bfhi(qraw.x);
    const float q2 = bflo(qraw.y), q3 = bfhi(qraw.y);

    // pipeline prologue: values for edges start..start+7, indices for +8..+15
    int iA = ssrc[min(start +      eidx, NE - 1)];
    int iB = ssrc[min(start +  4 + eidx, NE - 1)];
    uint2 rA = ldraw(vb, iA, sub);
    uint2 rB = ldraw(vb, iB, sub);
    int nA = ssrc[min(start +  8 + eidx, NE - 1)];
    int nB = ssrc[min(start + 12 + eidx, NE - 1)];

    float a0 = 0.f, a1 = 0.f, a2 = 0.f, a3 = 0.f, ws = 0.f;

    for (int p = start; p < end; p += 8) {
        // ---- half A: edges p+0..p+3 ----
        {
            float v0 = bflo(rA.x), v1 = bfhi(rA.x), v2 = bflo(rA.y), v3 = bfhi(rA.y);
            rA = ldraw(vb, nA, sub);                       // edges p+8..p+11
            nA = ssrc[min(p + 16 + eidx, NE - 1)];         // edges p+16..p+19
            float f0 = q0 + v0, f1 = q1 + v1, f2 = q2 + v2, f3 = q3 + v3;
            f0 = fmaxf(f0, ALPHA * f0); f1 = fmaxf(f1, ALPHA * f1);
            f2 = fmaxf(f2, ALPHA * f2); f3 = fmaxf(f3, ALPHA * f3);
            float x = f0 * ak0;
            x = fmaf(f1, ak1, x); x = fmaf(f2, ak2, x); x = fmaf(f3, ak3, x);
            x = dpp_add<0xB1>(x);    // quad xor1
            x = dpp_add<0x4E>(x);    // quad xor2 -> full head sum
            float w = (p + eidx < end) ? __expf(x) : 0.f;
            ws += w;
            a0 = fmaf(w, v0, a0); a1 = fmaf(w, v1, a1);
            a2 = fmaf(w, v2, a2); a3 = fmaf(w, v3, a3);
        }
        // ---- half B: edges p+4..p+7 ----
        {
            float v0 = bflo(rB.x), v1 = bfhi(rB.x), v2 = bflo(rB.y), v3 = bfhi(rB.y);
            rB = ldraw(vb, nB, sub);                       // edges p+12..p+15
            nB = ssrc[min(p + 20 + eidx, NE - 1)];         // edges p+20..p+23
            float f0 = q0 + v0, f1 = q1 + v1, f2 = q2 + v2, f3 = q3 + v3;
            f0 = fmaxf(f0, ALPHA * f0); f1 = fmaxf(f1, ALPHA * f1);
            f2 = fmaxf(f2, ALPHA * f2); f3 = fmaxf(f3, ALPHA * f3);
            float x = f0 * ak0;
            x = fmaf(f1, ak1, x); x = fmaf(f2, ak2, x); x = fmaf(f3, ak3, x);
            x = dpp_add<0xB1>(x);
            x = dpp_add<0x4E>(x);
            float w = (p + 4 + eidx < end) ? __expf(x) : 0.f;
            ws += w;
            a0 = fmaf(w, v0, a0); a1 = fmaf(w, v1, a1);
            a2 = fmaf(w, v2, a2); a3 = fmaf(w, v3, a3);
        }
    }

    // combine the 4 edge slots (xor16 then xor32)
    a0 += __shfl_xor(a0, 16); a1 += __shfl_xor(a1, 16);
    a2 += __shfl_xor(a2, 16); a3 += __shfl_xor(a3, 16);
    ws += __shfl_xor(ws, 16);
    a0 += __shfl_xor(a0, 32); a1 += __shfl_xor(a1, 32);
    a2 += __shfl_xor(a2, 32); a3 += __shfl_xor(a3, 32);
    ws += __shfl_xor(ws, 32);

    if (lane < 16) {
        float inv = (ws > 0.f) ? __frcp_rn(ws) : 1.0f;
        float r0 = a0 * inv, r1 = a1 * inv, r2 = a2 * inv, r3 = a3 * inv;
        r0 = fmaxf(r0, ALPHA * r0); r1 = fmaxf(r1, ALPHA * r1);
        r2 = fmaxf(r2, ALPHA * r2); r3 = fmaxf(r3, ALPHA * r3);
        *(float4*)(out + (size_t)node * 64 + sub * 4) = float4{r0, r1, r2, r3};
    }
}

extern "C" void kernel_launch(void* const* d_in, const int* in_sizes, int n_in,
                              void* d_out, int out_size, void* d_ws, size_t ws_size,
                              hipStream_t stream) {
    const float* nf   = (const float*)d_in[0];
    const float* Wq   = (const float*)d_in[1];
    const float* bq   = (const float*)d_in[2];
    const float* Wv   = (const float*)d_in[3];
    const float* bv   = (const float*)d_in[4];
    const float* ak   = (const float*)d_in[5];
    const int*   esrc = (const int*)d_in[6];
    const int*   etgt = (const int*)d_in[7];
    float* out = (float*)d_out;

    // workspace layout:
    //   qbf:     NN*64      u16  (12.8 MB)
    //   vbf:     NN*64      u16  (12.8 MB)
    //   offs:    NN+1       i32
    //   ssrc:    NE         i32  (6.4 MB)
    //   packed:  NE         u32  (6.4 MB)
    //   hist:    NPB*NBUCK  i32  (200 KB)
    //   colbase: NPB*NBUCK  i32  (200 KB)
    //   gtotal:  NBUCK      i32
    //   bbase:   NBUCK+1    i32
    unsigned short* qbf     = (unsigned short*)d_ws;
    unsigned short* vbf     = qbf + (size_t)NN * 64;
    int*            offs    = (int*)(vbf + (size_t)NN * 64);
    int*            ssrc    = offs + (NN + 1);
    unsigned int*   packed  = (unsigned int*)(ssrc + NE);
    int*            hist    = (int*)(packed + NE);
    int*            colbase = hist + NPB * NBUCK;
    int*            gtotal  = colbase + NPB * NBUCK;
    int*            bbase   = gtotal + NBUCK;

    hipMemsetAsync(gtotal, 0, NBUCK * sizeof(int), stream);

    transform_kernel<<<TBLKS, 256, 0, stream>>>(nf, Wq, bq, Wv, bv, qbf, vbf);
    bucket_count_kernel<<<NPB, 256, 0, stream>>>(etgt, hist, gtotal);
    base_scan_kernel<<<1, 256, 0, stream>>>(gtotal, bbase, offs);
    colbase_kernel<<<NBUCK, 256, 0, stream>>>(hist, bbase, colbase);
    partition_kernel<<<NPB, 256, 0, stream>>>(esrc, etgt, colbase, packed);
    bucket_csr_kernel<<<NBUCK, 256, 0, stream>>>(packed, bbase, offs, ssrc);
    gather_kernel<<<(NN * 64 + 255) / 256, 256, 0, stream>>>(qbf, vbf, ak, offs, ssrc, out);
}

// Round 9
// 128.254 us; speedup vs baseline: 3.1794x; 1.0579x over previous
//
#include <hip/hip_runtime.h>

#define NN 100000
#define NE 1600000
#define ALPHA 0.2f

#define BSH   9                          // 512 nodes per bucket
#define NPBK  512                        // nodes per bucket
#define NBUCK ((NN + NPBK - 1) / NPBK)   // 196 buckets
#define NPB   256                        // partition / count blocks
#define CHUNK ((NE + NPB - 1) / NPB)     // 6250 edges per block

#define MTILES (NN / 16)                 // 6250 (NN % 16 == 0)
#define TBLKS  ((MTILES + 3) / 4)        // 1563 transform blocks

typedef __attribute__((ext_vector_type(8))) short  short8;
typedef __attribute__((ext_vector_type(4))) float  f32x4;

// ---------------- bf16 helpers (RNE pack, cheap unpack) ---------------------
__device__ __forceinline__ unsigned short f2bf(float f) {
    unsigned int u = __builtin_bit_cast(unsigned int, f);
    u += 0x7FFFu + ((u >> 16) & 1u);
    return (unsigned short)(u >> 16);
}
__device__ __forceinline__ float bf2fs(unsigned short u) {
    return __builtin_bit_cast(float, (unsigned int)u << 16);
}
__device__ __forceinline__ float bflo(unsigned int u) {
    return __builtin_bit_cast(float, u << 16);
}
__device__ __forceinline__ float bfhi(unsigned int u) {
    return __builtin_bit_cast(float, u & 0xFFFF0000u);
}

// ---------------- DPP adds (all VALU, no DS pipe) ---------------------------
template<int CTRL>
__device__ __forceinline__ float dpp_add(float x) {
    int y = __builtin_amdgcn_update_dpp(0, __builtin_bit_cast(int, x),
                                        CTRL, 0xF, 0xF, true);
    return x + __builtin_bit_cast(float, y);
}

// ---------------- 256-thread block exclusive scan ---------------------------
__device__ __forceinline__ int block_excl_scan_256(int val, int* lds4) {
    const int lane = threadIdx.x & 63;
    const int wid  = threadIdx.x >> 6;
    int incl = val;
    #pragma unroll
    for (int off = 1; off < 64; off <<= 1) {
        int t = __shfl_up(incl, off);
        if (lane >= off) incl += t;
    }
    if (lane == 63) lds4[wid] = incl;
    __syncthreads();
    int wbase = 0;
    #pragma unroll
    for (int w = 0; w < 4; w++) if (w < wid) wbase += lds4[w];
    __syncthreads();
    return wbase + incl - val;
}

// ---------------------------------------------------------------------------
// Fused K1: blocks 0..NPB-1 do the bucket histogram; blocks NPB.. do the
// MFMA node transform (split-precision bf16, fp32-equivalent).
// C/D layout (HW-verified): col = lane&15, row = (lane>>4)*4 + reg.
// ---------------------------------------------------------------------------
__global__ __launch_bounds__(256) void fused_tc_kernel(
    const float* __restrict__ nf, const float* __restrict__ Wq, const float* __restrict__ bq,
    const float* __restrict__ Wv, const float* __restrict__ bv,
    unsigned short* __restrict__ qbf, unsigned short* __restrict__ vbf,
    const int* __restrict__ etgt, int* __restrict__ hist, int* __restrict__ gtotal)
{
    __shared__ short8 sB[2][2][8][64];   // 32 KB (transform branch)
    __shared__ float  sbias[128];
    __shared__ int    h[NBUCK];          // count branch
    const int tid = threadIdx.x;

    if (blockIdx.x < NPB) {
        // ---------------- bucket histogram ----------------
        const int blk = blockIdx.x;
        for (int i = tid; i < NBUCK; i += 256) h[i] = 0;
        __syncthreads();
        const int e0 = blk * CHUNK;
        const int e1 = min(e0 + CHUNK, NE);
        for (int e = e0 + tid; e < e1; e += 256)
            atomicAdd(&h[etgt[e] >> BSH], 1);
        __syncthreads();
        for (int i = tid; i < NBUCK; i += 256) {
            int c = h[i];
            hist[blk * NBUCK + i] = c;
            if (c) atomicAdd(&gtotal[i], c);
        }
        return;
    }

    // ---------------- MFMA transform ----------------
    if (tid < 64)       sbias[tid] = bq[tid];
    else if (tid < 128) sbias[tid] = bv[tid - 64];

    for (int slot = tid; slot < 2 * 8 * 64; slot += 256) {
        const int lane  = slot & 63;
        const int ntile = (slot >> 6) & 7;
        const int kstep = slot >> 9;
        const int j     = ntile * 16 + (lane & 15);
        const int kbase = kstep * 32 + (lane >> 4) * 8;
        const float* W  = (j < 64) ? Wq : Wv;
        const int jj    = j & 63;
        short8 hi, lo;
        #pragma unroll
        for (int r = 0; r < 8; r++) {
            float w = W[(kbase + r) * 64 + jj];
            unsigned short hh = f2bf(w);
            lo[r] = (short)f2bf(w - bf2fs(hh));
            hi[r] = (short)hh;
        }
        sB[0][kstep][ntile][lane] = hi;
        sB[1][kstep][ntile][lane] = lo;
    }
    __syncthreads();

    const int lane  = tid & 63;
    const int wv_   = tid >> 6;
    const int row16 = lane & 15;
    const int kg    = lane >> 4;
    const int tb    = blockIdx.x - NPB;

    for (int wt = tb * 4 + wv_; wt < MTILES; wt += TBLKS * 4) {
        const int row = wt * 16 + row16;

        short8 ah[2], al[2];
        #pragma unroll
        for (int s = 0; s < 2; s++) {
            const float* ap = nf + (size_t)row * 64 + s * 32 + kg * 8;
            #pragma unroll
            for (int r = 0; r < 8; r++) {
                float x = ap[r];
                unsigned short hh = f2bf(x);
                al[s][r] = (short)f2bf(x - bf2fs(hh));
                ah[s][r] = (short)hh;
            }
        }

        #pragma unroll
        for (int nt = 0; nt < 8; nt++) {
            f32x4 acc = {0.f, 0.f, 0.f, 0.f};
            #pragma unroll
            for (int s = 0; s < 2; s++) {
                short8 bh = sB[0][s][nt][lane];
                short8 bl = sB[1][s][nt][lane];
                acc = __builtin_amdgcn_mfma_f32_16x16x32_bf16(ah[s], bh, acc, 0, 0, 0);
                acc = __builtin_amdgcn_mfma_f32_16x16x32_bf16(al[s], bh, acc, 0, 0, 0);
                acc = __builtin_amdgcn_mfma_f32_16x16x32_bf16(ah[s], bl, acc, 0, 0, 0);
            }
            const int col = nt * 16 + (lane & 15);
            const float b = sbias[col];
            unsigned short* outp = (col < 64) ? qbf : vbf;
            const int jj    = col & 63;
            const int rbase = wt * 16 + (lane >> 4) * 4;
            #pragma unroll
            for (int r = 0; r < 4; r++)
                outp[(size_t)(rbase + r) * 64 + jj] = f2bf(acc[r] + b);
        }
    }
}

// ---------------------------------------------------------------------------
// colbase (absorbs base_scan): every block redundantly scans gtotal (196
// ints) for its bucket base, then scans its hist column across the 256
// partition blocks.
// ---------------------------------------------------------------------------
__global__ __launch_bounds__(256) void colbase_kernel(
    const int* __restrict__ hist, const int* __restrict__ gtotal,
    int* __restrict__ bbase, int* __restrict__ colbase, int* __restrict__ offs)
{
    __shared__ int lds4[4];
    __shared__ int sb[256];
    const int bk = blockIdx.x;
    const int t  = threadIdx.x;

    int gval = (t < NBUCK) ? gtotal[t] : 0;
    int gex  = block_excl_scan_256(gval, lds4);
    sb[t] = gex;
    if (t == bk) bbase[bk] = gex;
    if (bk == 0 && t == NBUCK - 1) { bbase[NBUCK] = gex + gval; offs[NN] = NE; }
    __syncthreads();
    const int myBase = sb[bk];
    __syncthreads();

    int val = hist[t * NBUCK + bk];
    int ex  = block_excl_scan_256(val, lds4);
    colbase[t * NBUCK + bk] = myBase + ex;
}

__global__ __launch_bounds__(256) void partition_kernel(
    const int* __restrict__ esrc, const int* __restrict__ etgt,
    const int* __restrict__ colbase, unsigned int* __restrict__ packed)
{
    __shared__ int cur[NBUCK];
    const int blk = blockIdx.x;
    for (int i = threadIdx.x; i < NBUCK; i += 256)
        cur[i] = colbase[blk * NBUCK + i];
    __syncthreads();
    const int e0 = blk * CHUNK;
    const int e1 = min(e0 + CHUNK, NE);
    for (int e = e0 + threadIdx.x; e < e1; e += 256) {
        int t = etgt[e], s = esrc[e];
        int bk = t >> BSH;
        int pos = atomicAdd(&cur[bk], 1);
        packed[pos] = (unsigned)s | ((unsigned)(t & (NPBK - 1)) << 17);
    }
}

__global__ __launch_bounds__(256) void bucket_csr_kernel(
    const unsigned int* __restrict__ packed, const int* __restrict__ bbase,
    int* __restrict__ offs, int* __restrict__ ssrc)
{
    __shared__ int cnt[NPBK];
    __shared__ int loff[NPBK];
    __shared__ int lds4[4];
    const int bk = blockIdx.x;
    const int s0 = bbase[bk], s1 = bbase[bk + 1];
    for (int i = threadIdx.x; i < NPBK; i += 256) cnt[i] = 0;
    __syncthreads();
    for (int e = s0 + threadIdx.x; e < s1; e += 256)
        atomicAdd(&cnt[packed[e] >> 17], 1);
    __syncthreads();
    int a0 = cnt[2 * threadIdx.x], a1 = cnt[2 * threadIdx.x + 1];
    int ex = block_excl_scan_256(a0 + a1, lds4);
    loff[2 * threadIdx.x]     = ex;
    loff[2 * threadIdx.x + 1] = ex + a0;
    __syncthreads();
    for (int i = threadIdx.x; i < NPBK; i += 256) {
        int node = (bk << BSH) + i;
        int g = s0 + loff[i];
        if (node < NN) offs[node] = g;
        cnt[i] = g;                      // becomes cursor
    }
    __syncthreads();
    for (int e = s0 + threadIdx.x; e < s1; e += 256) {
        unsigned p = packed[e];
        int tl  = p >> 17;
        int pos = atomicAdd(&cnt[tl], 1);
        ssrc[pos] = (int)(p & 0x1FFFFu);
    }
}

// ---------------------------------------------------------------------------
// Gather kernel v4: one wave per node; 4 edges per half-iteration.
// All prefetch positions clamp to end-1 (dup of node's last edge row, L1-hot)
// so no junk cross-node gathers. Logit: ak*leaky(f) = (.6ak)*f + (.4ak)*|f|
// with abs folded into fma modifiers; log2(e) folded into coefficients so
// w = v_exp_f32(x) directly.
// ---------------------------------------------------------------------------
__device__ __forceinline__ uint2 ldraw(const unsigned short* __restrict__ vb,
                                       int src, int sub) {
    return *(const uint2*)((const char*)vb + ((size_t)src << 7) + sub * 8);
}

__global__ __launch_bounds__(256) void gather_kernel(
    const unsigned short* __restrict__ qb, const unsigned short* __restrict__ vb,
    const float* __restrict__ ak,   // [16][4] row-major: ak[c*4+h]
    const int* __restrict__ offs, const int* __restrict__ ssrc,
    float* __restrict__ out)
{
    const int node = (blockIdx.x * 256 + threadIdx.x) >> 6;
    const int lane = threadIdx.x & 63;
    if (node >= NN) return;
    const int eidx = lane >> 4;      // edge slot 0..3
    const int sub  = lane & 15;
    const int h    = sub >> 2;
    const int cq   = sub & 3;

    const int start = offs[node];
    const int end   = offs[node + 1];

    if (start >= end) {
        if (lane < 16)
            *(float4*)(out + (size_t)node * 64 + sub * 4) = float4{0.f, 0.f, 0.f, 0.f};
        return;
    }
    const int end1 = end - 1;

    const float c6 = 0.6f * 1.44269504088896f;   // leaky+log2e folded
    const float c4 = 0.4f * 1.44269504088896f;
    float k0 = ak[(cq * 4 + 0) * 4 + h];
    float k1 = ak[(cq * 4 + 1) * 4 + h];
    float k2 = ak[(cq * 4 + 2) * 4 + h];
    float k3 = ak[(cq * 4 + 3) * 4 + h];
    const float a60 = c6 * k0, a40 = c4 * k0;
    const float a61 = c6 * k1, a41 = c4 * k1;
    const float a62 = c6 * k2, a42 = c4 * k2;
    const float a63 = c6 * k3, a43 = c4 * k3;

    uint2 qraw = *(const uint2*)((const char*)qb + ((size_t)node << 7) + sub * 8);
    const float q0 = bflo(qraw.x), q1 = bfhi(qraw.x);
    const float q2 = bflo(qraw.y), q3 = bfhi(qraw.y);

    // pipeline prologue (positions clamped node-locally)
    int iA = ssrc[min(start +      eidx, end1)];
    int iB = ssrc[min(start +  4 + eidx, end1)];
    uint2 rA = ldraw(vb, iA, sub);
    uint2 rB = ldraw(vb, iB, sub);
    int nA = ssrc[min(start +  8 + eidx, end1)];
    int nB = ssrc[min(start + 12 + eidx, end1)];

    float a0 = 0.f, a1 = 0.f, a2 = 0.f, a3 = 0.f, ws = 0.f;

    for (int p = start; p < end; p += 8) {
        // ---- half A: edges p+0..p+3 ----
        {
            float v0 = bflo(rA.x), v1 = bfhi(rA.x), v2 = bflo(rA.y), v3 = bfhi(rA.y);
            rA = ldraw(vb, nA, sub);                       // edges p+8..p+11
            nA = ssrc[min(p + 16 + eidx, end1)];
            float f0 = q0 + v0, f1 = q1 + v1, f2 = q2 + v2, f3 = q3 + v3;
            float x;
            x = f0 * a60;          x = fmaf(fabsf(f0), a40, x);
            x = fmaf(f1, a61, x);  x = fmaf(fabsf(f1), a41, x);
            x = fmaf(f2, a62, x);  x = fmaf(fabsf(f2), a42, x);
            x = fmaf(f3, a63, x);  x = fmaf(fabsf(f3), a43, x);
            x = dpp_add<0xB1>(x);
            x = dpp_add<0x4E>(x);
            float w = (p + eidx < end) ? __builtin_amdgcn_exp2f(x) : 0.f;
            ws += w;
            a0 = fmaf(w, v0, a0); a1 = fmaf(w, v1, a1);
            a2 = fmaf(w, v2, a2); a3 = fmaf(w, v3, a3);
        }
        // ---- half B: edges p+4..p+7 ----
        {
            float v0 = bflo(rB.x), v1 = bfhi(rB.x), v2 = bflo(rB.y), v3 = bfhi(rB.y);
            rB = ldraw(vb, nB, sub);                       // edges p+12..p+15
            nB = ssrc[min(p + 20 + eidx, end1)];
            float f0 = q0 + v0, f1 = q1 + v1, f2 = q2 + v2, f3 = q3 + v3;
            float x;
            x = f0 * a60;          x = fmaf(fabsf(f0), a40, x);
            x = fmaf(f1, a61, x);  x = fmaf(fabsf(f1), a41, x);
            x = fmaf(f2, a62, x);  x = fmaf(fabsf(f2), a42, x);
            x = fmaf(f3, a63, x);  x = fmaf(fabsf(f3), a43, x);
            x = dpp_add<0xB1>(x);
            x = dpp_add<0x4E>(x);
            float w = (p + 4 + eidx < end) ? __builtin_amdgcn_exp2f(x) : 0.f;
            ws += w;
            a0 = fmaf(w, v0, a0); a1 = fmaf(w, v1, a1);
            a2 = fmaf(w, v2, a2); a3 = fmaf(w, v3, a3);
        }
    }

    // combine the 4 edge slots (xor16 then xor32)
    a0 += __shfl_xor(a0, 16); a1 += __shfl_xor(a1, 16);
    a2 += __shfl_xor(a2, 16); a3 += __shfl_xor(a3, 16);
    ws += __shfl_xor(ws, 16);
    a0 += __shfl_xor(a0, 32); a1 += __shfl_xor(a1, 32);
    a2 += __shfl_xor(a2, 32); a3 += __shfl_xor(a3, 32);
    ws += __shfl_xor(ws, 32);

    if (lane < 16) {
        float inv = (ws > 0.f) ? __frcp_rn(ws) : 1.0f;
        float r0 = a0 * inv, r1 = a1 * inv, r2 = a2 * inv, r3 = a3 * inv;
        r0 = fmaxf(r0, ALPHA * r0); r1 = fmaxf(r1, ALPHA * r1);
        r2 = fmaxf(r2, ALPHA * r2); r3 = fmaxf(r3, ALPHA * r3);
        *(float4*)(out + (size_t)node * 64 + sub * 4) = float4{r0, r1, r2, r3};
    }
}

extern "C" void kernel_launch(void* const* d_in, const int* in_sizes, int n_in,
                              void* d_out, int out_size, void* d_ws, size_t ws_size,
                              hipStream_t stream) {
    const float* nf   = (const float*)d_in[0];
    const float* Wq   = (const float*)d_in[1];
    const float* bq   = (const float*)d_in[2];
    const float* Wv   = (const float*)d_in[3];
    const float* bv   = (const float*)d_in[4];
    const float* ak   = (const float*)d_in[5];
    const int*   esrc = (const int*)d_in[6];
    const int*   etgt = (const int*)d_in[7];
    float* out = (float*)d_out;

    // workspace layout:
    //   qbf:     NN*64      u16  (12.8 MB)
    //   vbf:     NN*64      u16  (12.8 MB)
    //   offs:    NN+1       i32
    //   ssrc:    NE         i32  (6.4 MB)
    //   packed:  NE         u32  (6.4 MB)
    //   hist:    NPB*NBUCK  i32  (200 KB)
    //   colbase: NPB*NBUCK  i32  (200 KB)
    //   gtotal:  NBUCK      i32
    //   bbase:   NBUCK+1    i32
    unsigned short* qbf     = (unsigned short*)d_ws;
    unsigned short* vbf     = qbf + (size_t)NN * 64;
    int*            offs    = (int*)(vbf + (size_t)NN * 64);
    int*            ssrc    = offs + (NN + 1);
    unsigned int*   packed  = (unsigned int*)(ssrc + NE);
    int*            hist    = (int*)(packed + NE);
    int*            colbase = hist + NPB * NBUCK;
    int*            gtotal  = colbase + NPB * NBUCK;
    int*            bbase   = gtotal + NBUCK;

    hipMemsetAsync(gtotal, 0, NBUCK * sizeof(int), stream);

    fused_tc_kernel<<<NPB + TBLKS, 256, 0, stream>>>(nf, Wq, bq, Wv, bv, qbf, vbf,
                                                     etgt, hist, gtotal);
    colbase_kernel<<<NBUCK, 256, 0, stream>>>(hist, gtotal, bbase, colbase, offs);
    partition_kernel<<<NPB, 256, 0, stream>>>(esrc, etgt, colbase, packed);
    bucket_csr_kernel<<<NBUCK, 256, 0, stream>>>(packed, bbase, offs, ssrc);
    gather_kernel<<<(NN * 64 + 255) / 256, 256, 0, stream>>>(qbf, vbf, ak, offs, ssrc, out);
}